// Round 3
// baseline (448.744 us; speedup 1.0000x reference)
//
#include <hip/hip_runtime.h>
#include <hip/hip_bf16.h>

#define OUT_F 2048
#define IN_F  2048

typedef __attribute__((ext_vector_type(8))) short bfx8;   // 8 bf16 (4 VGPR) MFMA A/B frag
typedef __attribute__((ext_vector_type(4))) short s16x4;  // 4 bf16 (8B)
typedef __attribute__((ext_vector_type(4))) float fx4;    // MFMA C/D frag

// round-to-nearest-even fp32 -> bf16 bits
__device__ __forceinline__ unsigned short f2bf(float f) {
  unsigned int u = __float_as_uint(f);
  u += 0x7FFFu + ((u >> 16) & 1u);
  return (unsigned short)(u >> 16);
}

// async global->LDS, 16B per lane. LDS dest must be wave-uniform base (HW adds lane*16).
__device__ __forceinline__ void async_copy16(const void* gsrc, void* ldst) {
  __builtin_amdgcn_global_load_lds(
      (const __attribute__((address_space(1))) unsigned int*)gsrc,
      (__attribute__((address_space(3))) unsigned int*)ldst,
      16, 0, 0);
}

// ---------------- W build ----------------

// one thread per packed byte-pair: writes 2 fp32 weights
__global__ __launch_bounds__(256) void k_dequant(const int* __restrict__ packed,
                                                 const float* __restrict__ scales,
                                                 float* __restrict__ Wf) {
  int i = blockIdx.x * 256 + threadIdx.x;          // [0, OUT_F*IN_F/2)
  int row = i >> 10;                               // IN_F/2 = 1024 per row
  int v = packed[i];
  float s = scales[row];
  float2 w;
  w.x = (float)((v & 0xF) - 8) * s;                // low nibble -> even col
  w.y = (float)(((v >> 4) & 0xF) - 8) * s;         // high nibble -> odd col
  reinterpret_cast<float2*>(Wf)[i] = w;
}

__global__ __launch_bounds__(256) void k_scatter(const float* __restrict__ vals,
                                                 const int* __restrict__ rows,
                                                 const int* __restrict__ cols,
                                                 float* __restrict__ Wf, int nnz) {
  int i = blockIdx.x * 256 + threadIdx.x;
  if (i < nnz)
    atomicAdd(Wf + (size_t)rows[i] * IN_F + cols[i], vals[i]);  // ALPHA = 1.0
}

// fp32 -> bf16, 8 elements/thread (grid must exactly cover n/8 threads)
__global__ __launch_bounds__(256) void k_f32_to_bf16x8(const float* __restrict__ in,
                                                       short* __restrict__ outp) {
  long long i = (long long)blockIdx.x * 256 + threadIdx.x;
  const float4* v = reinterpret_cast<const float4*>(in) + 2 * i;
  float4 a = v[0], b = v[1];
  bfx8 r;
  r[0] = (short)f2bf(a.x); r[1] = (short)f2bf(a.y);
  r[2] = (short)f2bf(a.z); r[3] = (short)f2bf(a.w);
  r[4] = (short)f2bf(b.x); r[5] = (short)f2bf(b.y);
  r[6] = (short)f2bf(b.z); r[7] = (short)f2bf(b.w);
  reinterpret_cast<bfx8*>(outp)[i] = r;
}

// ---------------- GEMM: C[M][N] = A[M][K] * B[N][K]^T, bf16 in / fp32 out ----------------
// m97 structure: 128x128 tile, BK=32, 4 waves (2x2), 4x4 16x16x32 frags/wave,
// global_load_lds width=16 staging, 2 barriers per K-step.

__global__ __launch_bounds__(256) void k_gemm_bt(const short* __restrict__ A,
                                                 const short* __restrict__ B,
                                                 float* __restrict__ C,
                                                 int M, int N, int K) {
  __shared__ __align__(16) short Asm[128 * 32];
  __shared__ __align__(16) short Bsm[128 * 32];

  const int tid  = threadIdx.x;
  const int lane = tid & 63;
  const int wave = tid >> 6;
  const int wr = wave >> 1, wc = wave & 1;     // wave -> 64x64 quadrant
  const int l15 = lane & 15, l16 = lane >> 4;

  // XCD-aware bijective swizzle (grid is a multiple of 8 here)
  int nwg = gridDim.x, bid = blockIdx.x;
  int swz = ((nwg & 7) == 0) ? ((bid & 7) * (nwg >> 3) + (bid >> 3)) : bid;
  int nbn = N / 128;
  int bm = swz / nbn, bn = swz % nbn;

  fx4 acc[4][4] = {};

  const short* Ablk = A + (size_t)bm * 128 * K;
  const short* Bblk = B + (size_t)bn * 128 * K;

  for (int k0 = 0; k0 < K; k0 += 32) {
    // stage A+B tiles: chunk c in [0,512): row=c>>2, k-elem=(c&3)*8; LDS byte = c*16
#pragma unroll
    for (int i = 0; i < 2; ++i) {
      int c = i * 256 + tid;
      int r = c >> 2, kc = (c & 3) * 8;
      const short* ga = Ablk + (size_t)r * K + k0 + kc;   // per-lane global addr
      const short* gb = Bblk + (size_t)r * K + k0 + kc;
      short* la = Asm + i * 2048 + wave * 512;            // wave-uniform LDS base
      short* lb = Bsm + i * 2048 + wave * 512;
      async_copy16(ga, la);
      async_copy16(gb, lb);
    }
    __syncthreads();   // compiler emits vmcnt(0) drain before s_barrier

    bfx8 a[4], b[4];
#pragma unroll
    for (int mi = 0; mi < 4; ++mi)
      a[mi] = *reinterpret_cast<const bfx8*>(Asm + (wr * 64 + mi * 16 + l15) * 32 + l16 * 8);
#pragma unroll
    for (int ni = 0; ni < 4; ++ni)
      b[ni] = *reinterpret_cast<const bfx8*>(Bsm + (wc * 64 + ni * 16 + l15) * 32 + l16 * 8);
#pragma unroll
    for (int mi = 0; mi < 4; ++mi)
#pragma unroll
      for (int ni = 0; ni < 4; ++ni)
        acc[mi][ni] = __builtin_amdgcn_mfma_f32_16x16x32_bf16(a[mi], b[ni], acc[mi][ni], 0, 0, 0);
    __syncthreads();
  }

  // C/D mapping (m89-verified): col = lane&15, row = (lane>>4)*4 + reg
  float* Cblk = C + (size_t)(bm * 128 + wr * 64) * N + bn * 128 + wc * 64;
#pragma unroll
  for (int mi = 0; mi < 4; ++mi)
#pragma unroll
    for (int ni = 0; ni < 4; ++ni)
#pragma unroll
      for (int r = 0; r < 4; ++r)
        Cblk[(size_t)(mi * 16 + l16 * 4 + r) * N + ni * 16 + l15] = acc[mi][ni][r];
}

// Fallback variant for small workspace: A is fp32 in global, reg-staged + converted.
__global__ __launch_bounds__(256) void k_gemm_bt_cvtA(const float* __restrict__ A,
                                                      const short* __restrict__ B,
                                                      float* __restrict__ C,
                                                      int M, int N, int K) {
  __shared__ __align__(16) short Asm[128 * 32];
  __shared__ __align__(16) short Bsm[128 * 32];

  const int tid  = threadIdx.x;
  const int lane = tid & 63;
  const int wave = tid >> 6;
  const int wr = wave >> 1, wc = wave & 1;
  const int l15 = lane & 15, l16 = lane >> 4;

  int nwg = gridDim.x, bid = blockIdx.x;
  int swz = ((nwg & 7) == 0) ? ((bid & 7) * (nwg >> 3) + (bid >> 3)) : bid;
  int nbn = N / 128;
  int bm = swz / nbn, bn = swz % nbn;

  fx4 acc[4][4] = {};

  const float* Ablk = A + (size_t)bm * 128 * K;
  const short* Bblk = B + (size_t)bn * 128 * K;

  for (int k0 = 0; k0 < K; k0 += 32) {
#pragma unroll
    for (int i = 0; i < 2; ++i) {
      int c = i * 256 + tid;
      int r = c >> 2, kc = (c & 3) * 8;
      const short* gb = Bblk + (size_t)r * K + k0 + kc;
      short* lb = Bsm + i * 2048 + wave * 512;
      async_copy16(gb, lb);
    }
    // A: 128x32 fp32, 4 floats/thread/issue, convert in regs, ds_write 8B
#pragma unroll
    for (int i = 0; i < 4; ++i) {
      int c = i * 256 + tid;
      int r = c >> 3, kc = (c & 7) * 4;
      float4 v = *reinterpret_cast<const float4*>(Ablk + (size_t)r * K + k0 + kc);
      s16x4 p;
      p[0] = (short)f2bf(v.x); p[1] = (short)f2bf(v.y);
      p[2] = (short)f2bf(v.z); p[3] = (short)f2bf(v.w);
      *reinterpret_cast<s16x4*>(Asm + r * 32 + kc) = p;
    }
    __syncthreads();

    bfx8 a[4], b[4];
#pragma unroll
    for (int mi = 0; mi < 4; ++mi)
      a[mi] = *reinterpret_cast<const bfx8*>(Asm + (wr * 64 + mi * 16 + l15) * 32 + l16 * 8);
#pragma unroll
    for (int ni = 0; ni < 4; ++ni)
      b[ni] = *reinterpret_cast<const bfx8*>(Bsm + (wc * 64 + ni * 16 + l15) * 32 + l16 * 8);
#pragma unroll
    for (int mi = 0; mi < 4; ++mi)
#pragma unroll
      for (int ni = 0; ni < 4; ++ni)
        acc[mi][ni] = __builtin_amdgcn_mfma_f32_16x16x32_bf16(a[mi], b[ni], acc[mi][ni], 0, 0, 0);
    __syncthreads();
  }

  float* Cblk = C + (size_t)(bm * 128 + wr * 64) * N + bn * 128 + wc * 64;
#pragma unroll
  for (int mi = 0; mi < 4; ++mi)
#pragma unroll
    for (int ni = 0; ni < 4; ++ni)
#pragma unroll
      for (int r = 0; r < 4; ++r)
        Cblk[(size_t)(mi * 16 + l16 * 4 + r) * N + ni * 16 + l15] = acc[mi][ni][r];
}

extern "C" void kernel_launch(void* const* d_in, const int* in_sizes, int n_in,
                              void* d_out, int out_size, void* d_ws, size_t ws_size,
                              hipStream_t stream) {
  const float* x      = (const float*)d_in[0];
  const int*   packed = (const int*)d_in[1];
  const float* scales = (const float*)d_in[2];
  const float* ovals  = (const float*)d_in[3];
  const int*   orows  = (const int*)d_in[4];
  const int*   ocols  = (const int*)d_in[5];
  float* out = (float*)d_out;

  const int tokens = in_sizes[0] / IN_F;   // 16384
  const int nnz    = in_sizes[3];          // 209715

  const size_t xb_bytes = (size_t)tokens * IN_F * sizeof(short);   // 64 MiB
  const size_t wf_bytes = (size_t)OUT_F * IN_F * sizeof(float);    // 16 MiB
  const size_t wb_bytes = (size_t)OUT_F * IN_F * sizeof(short);    //  8 MiB

  char* ws = (char*)d_ws;
  const int grid = (tokens / 128) * (OUT_F / 128);                 // 2048

  if (ws_size >= xb_bytes + wf_bytes + wb_bytes) {
    // fast path: pre-convert x to bf16
    short* xb = (short*)ws;
    float* Wf = (float*)(ws + xb_bytes);
    short* Wb = (short*)(ws + xb_bytes + wf_bytes);

    k_dequant<<<OUT_F * IN_F / 2 / 256, 256, 0, stream>>>(packed, scales, Wf);
    k_scatter<<<(nnz + 255) / 256, 256, 0, stream>>>(ovals, orows, ocols, Wf, nnz);
    k_f32_to_bf16x8<<<OUT_F * IN_F / 8 / 256, 256, 0, stream>>>(Wf, Wb);
    k_f32_to_bf16x8<<<(int)((size_t)tokens * IN_F / 8 / 256), 256, 0, stream>>>(x, xb);
    k_gemm_bt<<<grid, 256, 0, stream>>>(xb, Wb, out, tokens, OUT_F, IN_F);
  } else {
    // small-ws fallback: GEMM reads x fp32 directly (reg-staged convert)
    float* Wf = (float*)ws;
    short* Wb = (short*)(ws + wf_bytes);

    k_dequant<<<OUT_F * IN_F / 2 / 256, 256, 0, stream>>>(packed, scales, Wf);
    k_scatter<<<(nnz + 255) / 256, 256, 0, stream>>>(ovals, orows, ocols, Wf, nnz);
    k_f32_to_bf16x8<<<OUT_F * IN_F / 8 / 256, 256, 0, stream>>>(Wf, Wb);
    k_gemm_bt_cvtA<<<grid, 256, 0, stream>>>(x, Wb, out, tokens, OUT_F, IN_F);
  }
}

// Round 5
// 384.200 us; speedup vs baseline: 1.1680x; 1.1680x over previous
//
#include <hip/hip_runtime.h>
#include <hip/hip_bf16.h>

#define OUT_F 2048
#define IN_F  2048

typedef __attribute__((ext_vector_type(8))) short bfx8;   // 8 bf16 MFMA A/B frag
typedef __attribute__((ext_vector_type(4))) float fx4;    // MFMA C/D frag

// round-to-nearest-even fp32 -> bf16 bits
__device__ __forceinline__ unsigned short f2bf(float f) {
  unsigned int u = __float_as_uint(f);
  u += 0x7FFFu + ((u >> 16) & 1u);
  return (unsigned short)(u >> 16);
}

// async global->LDS, 16B per lane. LDS dest is wave-uniform base + lane*16 (m104).
__device__ __forceinline__ void async_copy16(const void* gsrc, void* ldst) {
  __builtin_amdgcn_global_load_lds(
      (const __attribute__((address_space(1))) unsigned int*)gsrc,
      (__attribute__((address_space(3))) unsigned int*)ldst,
      16, 0, 0);
}

// ---------------- W build ----------------

__global__ __launch_bounds__(256) void k_dequant(const int* __restrict__ packed,
                                                 const float* __restrict__ scales,
                                                 float* __restrict__ Wf) {
  int i = blockIdx.x * 256 + threadIdx.x;          // [0, OUT_F*IN_F/2)
  int row = i >> 10;                               // IN_F/2 = 1024 per row
  int v = packed[i];
  float s = scales[row];
  float2 w;
  w.x = (float)((v & 0xF) - 8) * s;                // low nibble -> even col
  w.y = (float)(((v >> 4) & 0xF) - 8) * s;         // high nibble -> odd col
  reinterpret_cast<float2*>(Wf)[i] = w;
}

__global__ __launch_bounds__(256) void k_scatter(const float* __restrict__ vals,
                                                 const int* __restrict__ rows,
                                                 const int* __restrict__ cols,
                                                 float* __restrict__ Wf, int nnz) {
  int i = blockIdx.x * 256 + threadIdx.x;
  if (i < nnz)
    atomicAdd(Wf + (size_t)rows[i] * IN_F + cols[i], vals[i]);  // ALPHA = 1.0
}

__global__ __launch_bounds__(256) void k_f32_to_bf16x8(const float* __restrict__ in,
                                                       short* __restrict__ outp) {
  long long i = (long long)blockIdx.x * 256 + threadIdx.x;
  const float4* v = reinterpret_cast<const float4*>(in) + 2 * i;
  float4 a = v[0], b = v[1];
  bfx8 r;
  r[0] = (short)f2bf(a.x); r[1] = (short)f2bf(a.y);
  r[2] = (short)f2bf(a.z); r[3] = (short)f2bf(a.w);
  r[4] = (short)f2bf(b.x); r[5] = (short)f2bf(b.y);
  r[6] = (short)f2bf(b.z); r[7] = (short)f2bf(b.w);
  reinterpret_cast<bfx8*>(outp)[i] = r;
}

// ---------------- GEMM: C[M][N] = A[M][K] * B[N][K]^T ----------------
// 256x256 tile, BK=64, 8 waves (2M x 4N), double-buffered 128 KiB LDS,
// counted vmcnt(8) (never 0 in main loop), XOR-swizzled LDS (T2),
// XCD chunked swizzle (T1), setprio around MFMA cluster (T5).
//
// LDS element swizzle (involution): stored_elem = logical_elem ^ ((row&7)<<3)
// applied on the GLOBAL SOURCE for global_load_lds (linear LDS dest, rule #21)
// and on the ds_read address. Each consecutive 8-lane group of a ds_read_b128
// covers all 8 16B chunks of a 128B row-stripe -> all 32 banks, conflict-free.

__global__ __launch_bounds__(512, 2) void k_gemm256(const short* __restrict__ A,
                                                    const short* __restrict__ B,
                                                    float* __restrict__ C,
                                                    int M, int N, int K) {
  extern __shared__ short smem[];          // As[2][256][64] ++ Bs[2][256][64] = 128 KiB
  short* As = smem;
  short* Bs = smem + 2 * 256 * 64;

  const int tid = threadIdx.x;
  const int l   = tid & 63;
  const int w   = tid >> 6;                // 0..7
  const int wr  = w >> 2;                  // 0..1 : C-row half (128 rows)
  const int wc  = w & 3;                   // 0..3 : C-col quarter (64 cols)
  const int l15 = l & 15, l16 = l >> 4;

  // T1: XCD chunked swizzle (nwg = 512, multiple of 8)
  int nwg = gridDim.x, bid = blockIdx.x;
  int swz = ((nwg & 7) == 0) ? ((bid & 7) * (nwg >> 3) + (bid >> 3)) : bid;
  int nbn = N >> 8;
  int bm = swz / nbn, bn = swz % nbn;

  const short* Ablk = A + (size_t)bm * 256 * K;
  const short* Bblk = B + (size_t)bn * 256 * K;

  // staging geometry: per gload issue, wave covers 8 rows x 64 elems (1 KiB LDS).
  // lane -> row offset l>>3, k-elems ((l&7)^(l>>3))*8 (pre-swizzled source).
  const int srow   = l >> 3;
  const int srcoff = (((l & 7) ^ (l >> 3)) << 3);

  fx4 acc[8][4] = {};
  const int NT = K >> 6;                   // 32 K-tiles

  // ---- prologue: stage K-tile 0 into buf 0, full drain ----
#pragma unroll
  for (int h = 0; h < 2; ++h)
#pragma unroll
    for (int j = 0; j < 2; ++j) {
      int row = h * 128 + w * 16 + j * 8;                    // wave-uniform
      async_copy16(Ablk + (size_t)(row + srow) * K + srcoff, As + row * 64);
      async_copy16(Bblk + (size_t)(row + srow) * K + srcoff, Bs + row * 64);
    }
  asm volatile("s_waitcnt vmcnt(0)" ::: "memory");
  __builtin_amdgcn_s_barrier();

  for (int kt = 0; kt < NT; ++kt) {
    const int c = kt & 1;
    const short* Ac = As + c * 256 * 64;
    const short* Bc = Bs + c * 256 * 64;

    // BAR_A: all waves done reading buf c^1 (lgkmcnt'd before their MFMAs)
    __builtin_amdgcn_s_barrier();
    __builtin_amdgcn_sched_barrier(0);

    if (kt + 1 < NT) {
      const int k0 = (kt + 1) << 6;
      short* An = As + (c ^ 1) * 256 * 64;
      short* Bn = Bs + (c ^ 1) * 256 * 64;
#pragma unroll
      for (int h = 0; h < 2; ++h)
#pragma unroll
        for (int j = 0; j < 2; ++j) {
          int row = h * 128 + w * 16 + j * 8;
          async_copy16(Ablk + (size_t)(row + srow) * K + k0 + srcoff, An + row * 64);
          async_copy16(Bblk + (size_t)(row + srow) * K + k0 + srcoff, Bn + row * 64);
        }
      // counted wait: tolerate exactly the 8 just-issued -> waits for buf c only
      asm volatile("s_waitcnt vmcnt(8)" ::: "memory");
    } else {
      asm volatile("s_waitcnt vmcnt(0)" ::: "memory");
    }
    // BAR_B: every wave's buf-c loads landed
    __builtin_amdgcn_s_barrier();
    __builtin_amdgcn_sched_barrier(0);

    // ---- compute K-tile c: 24 swizzled ds_read_b128 + 64 MFMA ----
    bfx8 bf[2][4];
#pragma unroll
    for (int ks = 0; ks < 2; ++ks)
#pragma unroll
      for (int ni = 0; ni < 4; ++ni) {
        int r = wc * 64 + ni * 16 + l15;
        bf[ks][ni] = *reinterpret_cast<const bfx8*>(
            Bc + r * 64 + (((ks * 4 + l16) ^ (l15 & 7)) << 3));
      }
    __builtin_amdgcn_s_setprio(1);
#pragma unroll
    for (int mi = 0; mi < 8; ++mi) {
      int r = wr * 128 + mi * 16 + l15;
      bfx8 a0 = *reinterpret_cast<const bfx8*>(
          Ac + r * 64 + ((l16 ^ (l15 & 7)) << 3));
      bfx8 a1 = *reinterpret_cast<const bfx8*>(
          Ac + r * 64 + (((4 + l16) ^ (l15 & 7)) << 3));
#pragma unroll
      for (int ni = 0; ni < 4; ++ni)
        acc[mi][ni] = __builtin_amdgcn_mfma_f32_16x16x32_bf16(a0, bf[0][ni], acc[mi][ni], 0, 0, 0);
#pragma unroll
      for (int ni = 0; ni < 4; ++ni)
        acc[mi][ni] = __builtin_amdgcn_mfma_f32_16x16x32_bf16(a1, bf[1][ni], acc[mi][ni], 0, 0, 0);
    }
    __builtin_amdgcn_s_setprio(0);
  }

  // ---- epilogue: C/D mapping col=lane&15, row=(lane>>4)*4+reg (m89) ----
  float* Cb = C + (size_t)(bm * 256 + wr * 128) * N + bn * 256 + wc * 64;
#pragma unroll
  for (int mi = 0; mi < 8; ++mi)
#pragma unroll
    for (int ni = 0; ni < 4; ++ni)
#pragma unroll
      for (int r = 0; r < 4; ++r)
        Cb[(size_t)(mi * 16 + l16 * 4 + r) * N + ni * 16 + l15] = acc[mi][ni][r];
}

extern "C" void kernel_launch(void* const* d_in, const int* in_sizes, int n_in,
                              void* d_out, int out_size, void* d_ws, size_t ws_size,
                              hipStream_t stream) {
  const float* x      = (const float*)d_in[0];
  const int*   packed = (const int*)d_in[1];
  const float* scales = (const float*)d_in[2];
  const float* ovals  = (const float*)d_in[3];
  const int*   orows  = (const int*)d_in[4];
  const int*   ocols  = (const int*)d_in[5];
  float* out = (float*)d_out;

  const int tokens = in_sizes[0] / IN_F;   // 16384
  const int nnz    = in_sizes[3];          // 209715

  const size_t xb_bytes = (size_t)tokens * IN_F * sizeof(short);   // 64 MiB
  const size_t wf_bytes = (size_t)OUT_F * IN_F * sizeof(float);    // 16 MiB

  char* ws = (char*)d_ws;
  short* xb = (short*)ws;
  float* Wf = (float*)(ws + xb_bytes);
  short* Wb = (short*)(ws + xb_bytes + wf_bytes);

  // enable 128 KiB dynamic LDS for the GEMM (idempotent; not a stream op)
  static_assert(sizeof(short) == 2, "");
  const int lds_bytes = 2 * 2 * 256 * 64 * (int)sizeof(short);     // 131072
  (void)hipFuncSetAttribute((const void*)k_gemm256,
                            hipFuncAttributeMaxDynamicSharedMemorySize, lds_bytes);

  k_dequant<<<OUT_F * IN_F / 2 / 256, 256, 0, stream>>>(packed, scales, Wf);
  k_scatter<<<(nnz + 255) / 256, 256, 0, stream>>>(ovals, orows, ocols, Wf, nnz);
  k_f32_to_bf16x8<<<OUT_F * IN_F / 8 / 256, 256, 0, stream>>>(Wf, Wb);
  k_f32_to_bf16x8<<<(int)((size_t)tokens * IN_F / 8 / 256), 256, 0, stream>>>(x, xb);

  const int grid = (tokens / 256) * (OUT_F / 256);                 // 64*8 = 512
  k_gemm256<<<grid, 512, lds_bytes, stream>>>(xb, Wb, out, tokens, OUT_F, IN_F);
}